// Round 8
// baseline (149.734 us; speedup 1.0000x reference)
//
#include <hip/hip_runtime.h>

// Problem constants (fixed by setup_inputs)
#define B_   8
#define C_   64
#define O_   64
#define H_   128
#define W_   128
#define HO_  128
#define WO_  128
#define K2_  9
#define MOFF 18          // 2*K*K offset channels
#define PLANE (H_*W_)    // 16384
#define KTOT 576         // C_*K2_

// Row-band geometry (R13): rows ho-2..ho+2, cols -2..129 (zero-padded).
// Two planes (kh = channel half), each [5][132] cells of 16B (8 bf16).
#define BROWS 5
#define BCOLS 132
#define PSTRIDE (BROWS*BCOLS*8)   // 5280 ushorts = 10,560 B per plane

typedef short bf16x8 __attribute__((ext_vector_type(8)));
typedef float f32x16 __attribute__((ext_vector_type(16)));
typedef float f32x2  __attribute__((ext_vector_type(2)));
typedef unsigned int u32x4 __attribute__((ext_vector_type(4)));

__device__ __forceinline__ unsigned short f2bf(float f) {
    // round-to-nearest-even fp32 -> bf16
    unsigned u = __float_as_uint(f);
    u += 0x7fff + ((u >> 16) & 1);
    return (unsigned short)(u >> 16);
}
__device__ __forceinline__ float bf2f(short v) {
    return __uint_as_float(((unsigned)(unsigned short)v) << 16);
}
// unpack u32 (2 bf16) -> 2 floats (1 inst each: shl / and)
__device__ __forceinline__ f32x2 unpk(unsigned w) {
    f32x2 r;
    r.x = __uint_as_float(w << 16);
    r.y = __uint_as_float(w & 0xffff0000u);
    return r;
}

// ---------------------------------------------------------------------------
// PREP (merged): blocks < 1024 do the NHWC transpose; blocks >= 1024 convert
// both weight tensors to bf16 TAP-MAJOR rows (R16 vectorized version).
// xt layout (chunk-major NHWC):
//   xt[((cc*B + b)*PLANE + y*W + px)*16 + cl] = bf16(x[((b*64+cc*16+cl)*H+y)*W+px])
// ---------------------------------------------------------------------------
__global__ __launch_bounds__(256) void prep_kernel(const float* __restrict__ x,
                                                   const float* __restrict__ w,
                                                   const float* __restrict__ w_off,
                                                   unsigned short* __restrict__ xt,
                                                   unsigned short* __restrict__ wbf) {
    __shared__ __align__(16) unsigned short T[64 * 132];  // stride 132: ushort4-aligned
    const int tid = threadIdx.x;
    if (blockIdx.x >= B_ * H_) {                // ---- weight conversion ----
        int i = (blockIdx.x - B_ * H_) * 256 + tid;   // 96*576 = 55296
        if (i < 96 * KTOT) {
            int o = i / KTOT, pos = i % KTOT;
            int cc = pos / 144, r = pos % 144, t = r / 16, cl = r % 16;
            int c = cc * 16 + cl;
            unsigned short v;
            if (o < O_)             v = f2bf(w[o * KTOT + c * 9 + t]);
            else if (o < O_ + MOFF) v = f2bf(w_off[(o - O_) * KTOT + c * 9 + t]);
            else                    v = 0;
            wbf[i] = v;
        }
        return;
    }
    // ---- NHWC transpose ----
    const int b = blockIdx.x & 7;
    const int y = blockIdx.x >> 3;
    const float4* src4 = (const float4*)(x + (size_t)b * C_ * PLANE + y * W_);
    for (int i = tid; i < 64 * 32; i += 256) {  // 2048 float4 cells, 8 iters
        int c = i >> 5, px4 = i & 31;
        float4 v = src4[c * (PLANE / 4) + px4];
        ushort4 t = { f2bf(v.x), f2bf(v.y), f2bf(v.z), f2bf(v.w) };
        *(ushort4*)&T[c * 132 + px4 * 4] = t;
    }
    __syncthreads();
    for (int j = tid; j < 128 * 4; j += 256) {
        int cc = j >> 7, px = j & 127;
        unsigned short* dst = xt + ((size_t)(cc * B_ + b) * PLANE + y * W_ + px) * 16;
        ushort4 v0 = { T[(cc*16+ 0)*132+px], T[(cc*16+ 1)*132+px],
                       T[(cc*16+ 2)*132+px], T[(cc*16+ 3)*132+px] };
        ushort4 v1 = { T[(cc*16+ 4)*132+px], T[(cc*16+ 5)*132+px],
                       T[(cc*16+ 6)*132+px], T[(cc*16+ 7)*132+px] };
        ushort4 v2 = { T[(cc*16+ 8)*132+px], T[(cc*16+ 9)*132+px],
                       T[(cc*16+10)*132+px], T[(cc*16+11)*132+px] };
        ushort4 v3 = { T[(cc*16+12)*132+px], T[(cc*16+13)*132+px],
                       T[(cc*16+14)*132+px], T[(cc*16+15)*132+px] };
        *(ushort4*)(dst)      = v0;
        *(ushort4*)(dst + 4)  = v1;
        *(ushort4*)(dst + 8)  = v2;
        *(ushort4*)(dst + 12) = v3;
    }
}

// ---------------------------------------------------------------------------
// FUSED offset-conv + deformable-conv (R17).
// R16 post-mortem: prefetch null; issue-floor arithmetic shows 88% stall on
// the per-tap dependency chain (lo read -> coords -> 4 corner ds_reads ->
// blend -> MFMA, ~400cy x 72 taps/wave serial at VGPR=64).
// R17 attacks the chain:
//   Phase A: DIRECT-GLOBAL B-fragments (regular-grid taps = contiguous 16B
//     reads from L2-hot xt; 64 lanes -> one 2KB coalesced line). No LDS, no
//     barriers; 9 fragments preloaded into regs per chunk (static-indexed).
//   Phase B: explicit 2-stage tap pipeline -- issue tap t+1's lo read +
//     coords + 4 corner ds_reads BEFORE blending tap t (named cur/nxt
//     structs, fully unrolled => static indexing, no scratch).
// Blend kept from R14/R15: uint4 corners, f32x2 lerp (v_pk ops),
// v_cvt_pk_bf16_f32 pack. Staging R15-style (prefetch was null).
// Out-of-band offsets (P~1e-4/tap): exec-masked slow path, exact gather.
// LDS = 21,120(band) + 9,216(lo) = 30,336 B; (256,4) => 128-reg budget.
// Tripwire: WRITE_SIZE > ~33MB or FETCH >> 13MB = spill = revert pipeline.
// ---------------------------------------------------------------------------
__global__ __launch_bounds__(256, 4) void fused_kernel(const unsigned short* __restrict__ xt,
        const unsigned short* __restrict__ wobf, const float* __restrict__ b_off,
        const unsigned short* __restrict__ wbf, const float* __restrict__ bias,
        float* __restrict__ out) {
    __shared__ __align__(16) unsigned short band[2 * PSTRIDE];   // 21,120 B
    __shared__ float lo[MOFF * 128];                             // 9,216 B
    const int tid  = threadIdx.x;
    const int id   = blockIdx.x;                // 1024
    const int b    = id & 7;                    // batch-per-XCD heuristic
    const int ho   = id >> 3;
    const int wv   = tid >> 6;                  // wave 0..3
    const int lane = tid & 63;
    const int m    = lane & 31;
    const int kh   = lane >> 5;                 // channel half
    const int pxg  = (wv << 5) + m;             // owned output pixel

    // ================= Phase A: offset conv, direct-global, no barriers ====
    f32x16 acc0 = {};
    for (int cc = 0; cc < 4; ++cc) {
        const unsigned short* xtk = xt + (size_t)(cc * B_ + b) * PLANE * 16 + kh * 8;
        bf16x8 sfr[9];                          // 36 VGPR, static-indexed
        #pragma unroll
        for (int ks = 0; ks < 9; ++ks) {
            const int y  = ho - 1 + ks / 3;
            const int xx = pxg - 1 + ks % 3;
            bf16x8 s = {};
            if (((unsigned)y < (unsigned)H_) && ((unsigned)xx < (unsigned)W_))
                s = *(const bf16x8*)(xtk + (y * W_ + xx) * 16);
            sfr[ks] = s;
        }
        #pragma unroll
        for (int ks = 0; ks < 9; ++ks) {
            bf16x8 a = *(const bf16x8*)&wobf[m * KTOT + cc * 144 + ks * 16 + kh * 8];
            acc0 = __builtin_amdgcn_mfma_f32_32x32x16_bf16(a, sfr[ks], acc0, 0, 0, 0);
        }
    }
    // offsets -> lo[mo][pxg]. lo is written and read by the SAME wave
    // (columns pxg of wave wv; kh-half exchange is wave-internal via the
    // in-order per-wave DS pipe) -> no barrier needed for lo itself.
    #pragma unroll
    for (int r = 0; r < 16; ++r) {
        int mo = (r & 3) + ((r >> 2) << 3) + (kh << 2);
        if (mo < MOFF) lo[mo * 128 + pxg] = acc0[r] + b_off[mo];
    }

    // ================= Phase B: deformable conv (per-wave M=64, N=32) ======
    // Coalesced band staging (R15 style: load + write inline).
    auto stage = [&](const unsigned short* xtc) {
        uint4 va[3], vb[3];
        #pragma unroll
        for (int it = 0; it < 3; ++it) {        // issue all loads first
            va[it] = (uint4){0, 0, 0, 0};
            vb[it] = (uint4){0, 0, 0, 0};
            int j = tid + it * 256;
            if (j < 5 * BCOLS) {
                int r = j / BCOLS, c = j - r * BCOLS;
                int y = ho - 2 + r, x = c - 2;
                if (((unsigned)y < (unsigned)H_) && ((unsigned)x < (unsigned)W_)) {
                    const uint4* gp = (const uint4*)(xtc + (y * W_ + x) * 16);
                    va[it] = gp[0];
                    vb[it] = gp[1];
                }
            }
        }
        #pragma unroll
        for (int it = 0; it < 3; ++it) {
            int j = tid + it * 256;
            if (j < 5 * BCOLS) {
                int r = j / BCOLS, c = j - r * BCOLS;
                int s = (r * BCOLS + c) * 8;
                *(uint4*)&band[s]           = va[it];
                *(uint4*)&band[PSTRIDE + s] = vb[it];
            }
        }
    };

    struct Tap {
        uint4 c00, c01, c10, c11;               // corner cells (16 regs)
        float wy, wx;
        int   y0, x0;
        int   oob;
    };
    auto mk_tap = [&](int ks) {
        Tap t;
        float py  = (float)(ho - 1 + ks / 3) + lo[(2 * ks) * 128 + pxg];
        float pxc = (float)(pxg - 1 + ks % 3) + lo[(2 * ks + 1) * 128 + pxg];
        float fy = floorf(py), fx = floorf(pxc);
        t.wy = py - fy;  t.wx = pxc - fx;
        t.y0 = (int)fy;  t.x0 = (int)fx;
        int rb_ = t.y0 - ho + 2, cb = t.x0 + 2;
        t.oob = ((unsigned)rb_ > 3u) || ((unsigned)cb > 130u);
        int rbc = min(max(rb_, 0), 3), cbc = min(max(cb, 0), 130);
        const unsigned short* bp = &band[kh * PSTRIDE + (rbc * BCOLS + cbc) * 8];
        t.c00 = *(const uint4*)bp;
        t.c01 = *(const uint4*)(bp + 8);
        t.c10 = *(const uint4*)(bp + BCOLS * 8);
        t.c11 = *(const uint4*)(bp + BCOLS * 8 + 8);
        return t;
    };

    f32x16 acc[2] = {};
    for (int cc = 0; cc < 4; ++cc) {
        const unsigned short* xtc = xt + (size_t)(cc * B_ + b) * PLANE * 16;
        if (cc) __syncthreads();            // prev chunk's band reads done
        stage(xtc);
        __syncthreads();                    // band ready (also syncs post-A drift)
        Tap cur = mk_tap(0);
        #pragma unroll
        for (int ks = 0; ks < 9; ++ks) {
            Tap nxt;
            if (ks < 8) nxt = mk_tap(ks + 1);   // issue next tap's reads early
            // ---- blend cur (packed-pair lerp) ----
            const f32x2 wx2 = { cur.wx, cur.wx };
            const f32x2 wy2 = { cur.wy, cur.wy };
            u32x4 vr;
            #pragma unroll
            for (int pq = 0; pq < 4; ++pq) {
                unsigned w00 = (pq==0)?cur.c00.x:(pq==1)?cur.c00.y:(pq==2)?cur.c00.z:cur.c00.w;
                unsigned w01 = (pq==0)?cur.c01.x:(pq==1)?cur.c01.y:(pq==2)?cur.c01.z:cur.c01.w;
                unsigned w10 = (pq==0)?cur.c10.x:(pq==1)?cur.c10.y:(pq==2)?cur.c10.z:cur.c10.w;
                unsigned w11 = (pq==0)?cur.c11.x:(pq==1)?cur.c11.y:(pq==2)?cur.c11.z:cur.c11.w;
                f32x2 a2 = unpk(w00), b2 = unpk(w01);
                f32x2 c2 = unpk(w10), d2 = unpk(w11);
                f32x2 top = a2 + wx2 * (b2 - a2);     // v_pk ops on CDNA
                f32x2 bot = c2 + wx2 * (d2 - c2);
                f32x2 r2  = top + wy2 * (bot - top);
                unsigned pk;
                asm("v_cvt_pk_bf16_f32 %0, %1, %2" : "=v"(pk) : "v"(r2.x), "v"(r2.y));
                vr[pq] = pk;
            }
            bf16x8 v = __builtin_bit_cast(bf16x8, vr);
            // rare slow path: offsets outside the band -> exact global gather
            if (__builtin_expect(__any(cur.oob), 0)) {
                if (cur.oob) {
                    float wy = cur.wy, wx = cur.wx;
                    float s8[8];
                    #pragma unroll
                    for (int j = 0; j < 8; ++j) s8[j] = 0.f;
                    #pragma unroll
                    for (int c2i = 0; c2i < 4; ++c2i) {
                        int yy = cur.y0 + (c2i >> 1);
                        int xx = cur.x0 + (c2i & 1);
                        bool valid = ((unsigned)yy < (unsigned)H_) && ((unsigned)xx < (unsigned)W_);
                        int yc = min(max(yy, 0), H_ - 1);
                        int xc = min(max(xx, 0), W_ - 1);
                        float wgt = ((c2i >> 1) ? wy : 1.f - wy) * ((c2i & 1) ? wx : 1.f - wx);
                        wgt = valid ? wgt : 0.f;
                        const unsigned short* rp = xtc + (yc * W_ + xc) * 16 + kh * 8;
                        bf16x8 u = *(const bf16x8*)rp;
                        #pragma unroll
                        for (int j = 0; j < 8; ++j) s8[j] += wgt * bf2f(u[j]);
                    }
                    #pragma unroll
                    for (int j = 0; j < 8; ++j) v[j] = (short)f2bf(s8[j]);
                }
            }
            // MFMA: M=64 via two A-rows; A-fragments lazy (L2-hot wbf)
            bf16x8 a0 = *(const bf16x8*)&wbf[m * KTOT + cc * 144 + ks * 16 + kh * 8];
            bf16x8 a1 = *(const bf16x8*)&wbf[(32 + m) * KTOT + cc * 144 + ks * 16 + kh * 8];
            acc[0] = __builtin_amdgcn_mfma_f32_32x32x16_bf16(a0, v, acc[0], 0, 0, 0);
            acc[1] = __builtin_amdgcn_mfma_f32_32x32x16_bf16(a1, v, acc[1], 0, 0, 0);
            if (ks < 8) cur = nxt;              // reg rename after unroll
        }
    }

    // epilogue: D col = pixel (pxg), row = out channel (+32 for acc[1])
    {
        float* op = out + (size_t)b * O_ * PLANE + ho * WO_ + pxg;
        #pragma unroll
        for (int nt = 0; nt < 2; ++nt) {
            #pragma unroll
            for (int r = 0; r < 16; ++r) {
                int mo = (nt << 5) + (r & 3) + ((r >> 2) << 3) + (kh << 2);
                __builtin_nontemporal_store(acc[nt][r] + bias[mo], op + (size_t)mo * PLANE);
            }
        }
    }
}

// ---------------------------------------------------------------------------
extern "C" void kernel_launch(void* const* d_in, const int* in_sizes, int n_in,
                              void* d_out, int out_size, void* d_ws, size_t ws_size,
                              hipStream_t stream) {
    const float* x     = (const float*)d_in[0];
    const float* w_off = (const float*)d_in[1];
    const float* b_off = (const float*)d_in[2];
    const float* w     = (const float*)d_in[3];
    const float* bias  = (const float*)d_in[4];
    float* out = (float*)d_out;

    unsigned short* wbf  = (unsigned short*)d_ws;                   // 72 KB (tap-major)
    unsigned short* wobf = wbf + O_ * KTOT;                         // 36 KB (tap-major)
    unsigned short* xt   = wobf + 32 * KTOT;                        // 16.78 MB chunk-major

    const int wblocks = (96 * KTOT + 255) / 256;                    // 216
    prep_kernel <<<B_ * H_ + wblocks, 256, 0, stream>>>(x, w, w_off, xt, wbf);
    fused_kernel<<<B_ * HO_, 256, 0, stream>>>(xt, wobf, b_off, wbf, bias, out);
}